// Round 1
// baseline (1346.128 us; speedup 1.0000x reference)
//
#include <hip/hip_runtime.h>

#define DIM  4096
#define NH   32
#define NKV  8
#define HD   128
#define BSZ  2
#define TSEQ 2048

typedef __bf16 bf16x8 __attribute__((ext_vector_type(8)));
typedef unsigned short ushort8v __attribute__((ext_vector_type(8)));
typedef float f32x4 __attribute__((ext_vector_type(4)));

typedef void GV __attribute__((address_space(1)));
typedef void LV __attribute__((address_space(3)));

__device__ __forceinline__ unsigned short f2bf(float f) {
  unsigned u = __builtin_bit_cast(unsigned, f);
  u += 0x7FFFu + ((u >> 16) & 1u);           // RNE
  return (unsigned short)(u >> 16);
}
__device__ __forceinline__ float bf2f(unsigned short b) {
  unsigned u = ((unsigned)b) << 16;
  return __builtin_bit_cast(float, u);
}
// async global->LDS, 16B per lane. LDS dest must be wave-uniform-base + lane*16.
__device__ __forceinline__ void gload16(const unsigned short* g, unsigned short* l) {
  __builtin_amdgcn_global_load_lds((GV*)g, (LV*)l, 16, 0, 0);
}
__device__ __forceinline__ f32x4 mfma16(bf16x8 a, bf16x8 b, f32x4 c) {
  return __builtin_amdgcn_mfma_f32_16x16x32_bf16(a, b, c, 0, 0, 0);
}

// ---- dtype detect: freqs_cis[0] word is 0x3F800000 (fp32 cos(0)=1) or 0x00003F80 (bf16 pair) ----
__global__ void detect_dtype(const unsigned int* __restrict__ fc, int* __restrict__ flag) {
  if (threadIdx.x == 0 && blockIdx.x == 0)
    *flag = (fc[0] == 0x3F800000u) ? 0 : 1;   // 1 => inputs are bf16
}

// ---- x -> bf16 bits (copy if already bf16). 4 elems/thread ----
__global__ void cast_x(const void* __restrict__ src, unsigned short* __restrict__ dst,
                       const int* __restrict__ flag) {
  long t = (long)blockIdx.x * 256 + threadIdx.x;   // element group of 4
  if (*flag) {
    ((uint2*)dst)[t] = ((const uint2*)src)[t];
  } else {
    float4 f = ((const float4*)src)[t];
    ushort4 o;
    o.x = f2bf(f.x); o.y = f2bf(f.y); o.z = f2bf(f.z); o.w = f2bf(f.w);
    ((ushort4*)dst)[t] = o;
  }
}

// ---- transpose + cast: src (R x C) -> dst (C x R) bf16 ----
__global__ void transpose_cast(const void* __restrict__ src, unsigned short* __restrict__ dst,
                               int R, int C, const int* __restrict__ flag) {
  __shared__ unsigned short tile[32][33];   // +1 pad
  const int isbf = *flag;
  const int c0 = blockIdx.x * 32, r0 = blockIdx.y * 32;
  const int tx = threadIdx.x, ty = threadIdx.y;   // 32 x 8
  if (isbf) {
    const unsigned short* s = (const unsigned short*)src;
#pragma unroll
    for (int i = 0; i < 4; ++i)
      tile[ty + i * 8][tx] = s[(long)(r0 + ty + i * 8) * C + c0 + tx];
  } else {
    const float* s = (const float*)src;
#pragma unroll
    for (int i = 0; i < 4; ++i)
      tile[ty + i * 8][tx] = f2bf(s[(long)(r0 + ty + i * 8) * C + c0 + tx]);
  }
  __syncthreads();
#pragma unroll
  for (int i = 0; i < 4; ++i)
    dst[(long)(c0 + ty + i * 8) * R + r0 + tx] = tile[tx][ty + i * 8];
}

// ---- GEMM: C(MxN) = A(MxK,row) * Bt(NxK,row)^T ; bf16 in, fp32 acc ----
// outMode: 0=fp32 out, 1=bf16 out, 2=by *flag (1->bf16)
__global__ __launch_bounds__(256) void gemm_bt(const unsigned short* __restrict__ A,
                                               const unsigned short* __restrict__ Bt,
                                               void* __restrict__ Cv,
                                               int M, int N, int K, int outMode,
                                               const int* __restrict__ flag) {
  __shared__ unsigned short As[128 * 32];
  __shared__ unsigned short Bs[128 * 32];
  const int tid = threadIdx.x;
  const int lane = tid & 63, wave = tid >> 6;
  const int wm = (wave >> 1) * 64, wn = (wave & 1) * 64;
  const int lm = lane & 15, quad = lane >> 4;
  const long tileM = (long)blockIdx.y * 128, tileN = (long)blockIdx.x * 128;
  f32x4 acc[4][4] = {};
  const int r0 = tid >> 2, c0 = (tid & 3) * 8;
  const unsigned short* Ap = A + (tileM + r0) * (long)K + c0;
  const unsigned short* Bp = Bt + (tileN + r0) * (long)K + c0;
  for (int kt = 0; kt < K; kt += 32) {
    __syncthreads();
    gload16(Ap + kt, &As[tid * 8]);
    gload16(Ap + 64 * (long)K + kt, &As[2048 + tid * 8]);
    gload16(Bp + kt, &Bs[tid * 8]);
    gload16(Bp + 64 * (long)K + kt, &Bs[2048 + tid * 8]);
    __syncthreads();
    bf16x8 af[4], bfr[4];
#pragma unroll
    for (int i = 0; i < 4; ++i)
      af[i] = __builtin_bit_cast(bf16x8, *(const ushort8v*)&As[(wm + i * 16 + lm) * 32 + quad * 8]);
#pragma unroll
    for (int j = 0; j < 4; ++j)
      bfr[j] = __builtin_bit_cast(bf16x8, *(const ushort8v*)&Bs[(wn + j * 16 + lm) * 32 + quad * 8]);
#pragma unroll
    for (int i = 0; i < 4; ++i)
#pragma unroll
      for (int j = 0; j < 4; ++j)
        acc[i][j] = mfma16(af[i], bfr[j], acc[i][j]);
  }
  const int obf = (outMode == 2) ? *flag : outMode;
  if (obf) {
    unsigned short* C = (unsigned short*)Cv;
#pragma unroll
    for (int i = 0; i < 4; ++i)
#pragma unroll
      for (int j = 0; j < 4; ++j)
#pragma unroll
        for (int r = 0; r < 4; ++r)
          C[(tileM + wm + i * 16 + quad * 4 + r) * (long)N + tileN + wn + j * 16 + lm] =
              f2bf(acc[i][j][r]);
  } else {
    float* C = (float*)Cv;
#pragma unroll
    for (int i = 0; i < 4; ++i)
#pragma unroll
      for (int j = 0; j < 4; ++j)
#pragma unroll
        for (int r = 0; r < 4; ++r)
          C[(tileM + wm + i * 16 + quad * 4 + r) * (long)N + tileN + wn + j * 16 + lm] =
              acc[i][j][r];
  }
}

// ---- split qkv rows, apply RoPE to q/k, reorder to (B,H,T,HD) ----
// qkv row (per b,t): [q 4096 | k 1024 | v 1024].  grid (12, B*T), block 256 -> p in [0,3072)
__global__ void rope_split(const unsigned short* __restrict__ qkv, const void* __restrict__ fcv,
                           const int* __restrict__ flag,
                           unsigned short* __restrict__ q, unsigned short* __restrict__ k,
                           unsigned short* __restrict__ v) {
  const int p = blockIdx.x * 256 + threadIdx.x;
  const int bt = blockIdx.y;
  const int b = bt >> 11, t = bt & (TSEQ - 1);
  const int isbf = *flag;
  const unsigned short* row = qkv + (long)bt * 6144;
  if (p < 2560) {   // rope on q (p<2048) or k
    int h, i;
    const unsigned short* srcp;
    unsigned short* dstp;
    if (p < 2048) {
      h = p >> 6; i = p & 63;
      srcp = row + h * 128 + 2 * i;
      dstp = q + ((long)(b * NH + h) * TSEQ + t) * HD + 2 * i;
    } else {
      int pp = p - 2048;
      h = pp >> 6; i = pp & 63;
      srcp = row + 4096 + h * 128 + 2 * i;
      dstp = k + ((long)(b * NKV + h) * TSEQ + t) * HD + 2 * i;
    }
    float c, s;
    long fo = ((long)t * 64 + i) * 2;
    if (isbf) {
      const unsigned short* fu = (const unsigned short*)fcv;
      c = bf2f(fu[fo]); s = bf2f(fu[fo + 1]);
    } else {
      const float* ff = (const float*)fcv;
      c = ff[fo]; s = ff[fo + 1];
    }
    float x0 = bf2f(srcp[0]), x1 = bf2f(srcp[1]);
    dstp[0] = f2bf(x0 * c - x1 * s);
    dstp[1] = f2bf(x1 * c + x0 * s);
  } else {          // copy v pair
    int pp = p - 2560;
    int h = pp >> 6, i = pp & 63;
    const unsigned short* srcp = row + 5120 + h * 128 + 2 * i;
    unsigned short* dstp = v + ((long)(b * NKV + h) * TSEQ + t) * HD + 2 * i;
    dstp[0] = srcp[0];
    dstp[1] = srcp[1];
  }
}

// ---- flash attention: 64 q-rows/block (16/wave), 32-key tiles, online softmax ----
// q:(B,NH,T,HD) k,v:(B,NKV,T,HD) bf16 -> y:(B*T, DIM) bf16 (col = h*128+d)
__global__ __launch_bounds__(256) void flash_attn(const unsigned short* __restrict__ q,
                                                  const unsigned short* __restrict__ k,
                                                  const unsigned short* __restrict__ v,
                                                  unsigned short* __restrict__ y) {
  __shared__ unsigned short Ks[32 * 128];    // (key, d) row-major
  __shared__ unsigned short Vt[128 * 40];    // (d, key), stride 40 (16B-aligned rows)
  __shared__ unsigned short Pl[4][16 * 40];  // per-wave P, stride 40
  const int tid = threadIdx.x;
  const int lane = tid & 63, wave = tid >> 6;
  const int lm = lane & 15, quad = lane >> 4;
  const int bh = blockIdx.y, b = bh >> 5, h = bh & 31, kvh = h >> 2;
  const int q0 = blockIdx.x * 64;
  const unsigned short* Qb = q + ((long)(b * NH + h) * TSEQ + q0 + wave * 16) * HD;
  const unsigned short* Kb = k + (long)(b * NKV + kvh) * TSEQ * HD;
  const unsigned short* Vb = v + (long)(b * NKV + kvh) * TSEQ * HD;
  // Q fragments (A-operand layout): m=lm (q row), k = ks*32 + quad*8 + j
  bf16x8 qf[4];
#pragma unroll
  for (int ks = 0; ks < 4; ++ks)
    qf[ks] = __builtin_bit_cast(bf16x8, *(const ushort8v*)(Qb + lm * HD + ks * 32 + quad * 8));
  f32x4 o[8] = {};
  float mi[4] = {-INFINITY, -INFINITY, -INFINITY, -INFINITY};
  float li[4] = {0.f, 0.f, 0.f, 0.f};
  const float scale = 0.08838834764831845f;  // 1/sqrt(128)
  const int vkey = tid & 31, vdb = (tid >> 5) * 16;
  const int ktiles = q0 / 32 + 2;            // keys [0, q0+64)
  for (int kt = 0; kt < ktiles; ++kt) {
    __syncthreads();
    gload16(Kb + kt * 4096 + tid * 8, &Ks[tid * 8]);
    gload16(Kb + kt * 4096 + 2048 + tid * 8, &Ks[2048 + tid * 8]);
    {  // V tile transposed into Vt
      const unsigned short* vs = Vb + kt * 4096 + vkey * 128 + vdb;
      ushort8v v0 = *(const ushort8v*)vs;
      ushort8v v1 = *(const ushort8v*)(vs + 8);
#pragma unroll
      for (int i = 0; i < 8; ++i) {
        Vt[(vdb + i) * 40 + vkey] = v0[i];
        Vt[(vdb + 8 + i) * 40 + vkey] = v1[i];
      }
    }
    __syncthreads();
    // S = Q K^T  (two 16-key column blocks)
    f32x4 sA = {}, sB = {};
#pragma unroll
    for (int ks = 0; ks < 4; ++ks) {
      bf16x8 kf0 = __builtin_bit_cast(bf16x8, *(const ushort8v*)&Ks[lm * 128 + ks * 32 + quad * 8]);
      bf16x8 kf1 = __builtin_bit_cast(bf16x8, *(const ushort8v*)&Ks[(16 + lm) * 128 + ks * 32 + quad * 8]);
      sA = mfma16(qf[ks], kf0, sA);
      sB = mfma16(qf[ks], kf1, sB);
    }
    // scale + causal mask + online softmax (rows = quad*4+r, cols = lm / 16+lm)
    const int qg0 = q0 + wave * 16 + quad * 4;
    const int kg0 = kt * 32 + lm, kg1 = kt * 32 + 16 + lm;
    float p0[4], p1[4], al[4];
#pragma unroll
    for (int r = 0; r < 4; ++r) {
      const int qg = qg0 + r;
      float a = sA[r] * scale, bv = sB[r] * scale;
      if (kg0 > qg) a = -1e30f;
      if (kg1 > qg) bv = -1e30f;
      float rm = fmaxf(a, bv);
      rm = fmaxf(rm, __shfl_xor(rm, 1, 16));
      rm = fmaxf(rm, __shfl_xor(rm, 2, 16));
      rm = fmaxf(rm, __shfl_xor(rm, 4, 16));
      rm = fmaxf(rm, __shfl_xor(rm, 8, 16));
      float mn = fmaxf(mi[r], rm);
      al[r] = __expf(mi[r] - mn);
      mi[r] = mn;
      p0[r] = __expf(a - mn);
      p1[r] = __expf(bv - mn);
      float rs = p0[r] + p1[r];
      rs += __shfl_xor(rs, 1, 16);
      rs += __shfl_xor(rs, 2, 16);
      rs += __shfl_xor(rs, 4, 16);
      rs += __shfl_xor(rs, 8, 16);
      li[r] = li[r] * al[r] + rs;
    }
#pragma unroll
    for (int db = 0; db < 8; ++db)
#pragma unroll
      for (int r = 0; r < 4; ++r)
        o[db][r] *= al[r];
    // P: C/D layout -> LDS -> A-operand layout (wave-private, in-order DS ops)
    unsigned short* PlW = &Pl[wave][0];
#pragma unroll
    for (int r = 0; r < 4; ++r) {
      PlW[(quad * 4 + r) * 40 + lm] = f2bf(p0[r]);
      PlW[(quad * 4 + r) * 40 + 16 + lm] = f2bf(p1[r]);
    }
    bf16x8 pf = __builtin_bit_cast(bf16x8, *(const ushort8v*)&PlW[lm * 40 + quad * 8]);
#pragma unroll
    for (int db = 0; db < 8; ++db) {
      bf16x8 vf = __builtin_bit_cast(bf16x8, *(const ushort8v*)&Vt[(db * 16 + lm) * 40 + quad * 8]);
      o[db] = mfma16(pf, vf, o[db]);
    }
  }
  float inv[4];
#pragma unroll
  for (int r = 0; r < 4; ++r) inv[r] = 1.0f / li[r];
  unsigned short* yo = y + ((long)b * TSEQ + q0 + wave * 16 + quad * 4) * DIM + h * 128 + lm;
#pragma unroll
  for (int r = 0; r < 4; ++r)
#pragma unroll
    for (int db = 0; db < 8; ++db)
      yo[(long)r * DIM + db * 16] = f2bf(o[db][r] * inv[r]);
}

extern "C" void kernel_launch(void* const* d_in, const int* in_sizes, int n_in,
                              void* d_out, int out_size, void* d_ws, size_t ws_size,
                              hipStream_t stream) {
  const void* x  = d_in[0];
  const void* fc = d_in[1];
  const void* wq = d_in[2];
  const void* wk = d_in[3];
  const void* wv = d_in[4];
  const void* wo = d_in[5];
  char* ws = (char*)d_ws;
  int* flag            = (int*)ws;                          // 256 B reserved
  unsigned short* xb   = (unsigned short*)(ws + 256);       // 16,777,216 elems (reused as y)
  unsigned short* wqkvT = xb + 16777216L;                   // 25,165,824 elems (reused as q/k/v)
  unsigned short* woT  = wqkvT + 25165824L;                 // 16,777,216 elems
  unsigned short* qkvb = woT + 16777216L;                   // 25,165,824 elems
  unsigned short* qb = wqkvT;
  unsigned short* kb = qb + 16777216L;
  unsigned short* vb = kb + 4194304L;
  unsigned short* yb = xb;

  detect_dtype<<<dim3(1), dim3(64), 0, stream>>>((const unsigned int*)fc, flag);
  cast_x<<<dim3(16384), dim3(256), 0, stream>>>(x, xb, flag);
  transpose_cast<<<dim3(128, 128), dim3(32, 8), 0, stream>>>(wq, wqkvT, 4096, 4096, flag);
  transpose_cast<<<dim3(32, 128), dim3(32, 8), 0, stream>>>(wk, wqkvT + 4096L * 4096, 4096, 1024, flag);
  transpose_cast<<<dim3(32, 128), dim3(32, 8), 0, stream>>>(wv, wqkvT + 5120L * 4096, 4096, 1024, flag);
  transpose_cast<<<dim3(128, 128), dim3(32, 8), 0, stream>>>(wo, woT, 4096, 4096, flag);
  gemm_bt<<<dim3(48, 32), dim3(256), 0, stream>>>(xb, wqkvT, (void*)qkvb, 4096, 6144, 4096, 1, flag);
  rope_split<<<dim3(12, 4096), dim3(256), 0, stream>>>(qkvb, fc, flag, qb, kb, vb);
  flash_attn<<<dim3(32, 64), dim3(256), 0, stream>>>(qb, kb, vb, yb);
  gemm_bt<<<dim3(32, 32), dim3(256), 0, stream>>>(yb, woT, d_out, 4096, 4096, 4096, 2, flag);
}

// Round 2
// 978.584 us; speedup vs baseline: 1.3756x; 1.3756x over previous
//
#include <hip/hip_runtime.h>

#define DIM  4096
#define NH   32
#define NKV  8
#define HD   128
#define BSZ  2
#define TSEQ 2048

typedef __bf16 bf16x8 __attribute__((ext_vector_type(8)));
typedef unsigned short ushort8v __attribute__((ext_vector_type(8)));
typedef float f32x4 __attribute__((ext_vector_type(4)));

typedef void GV __attribute__((address_space(1)));
typedef void LV __attribute__((address_space(3)));

__device__ __forceinline__ unsigned short f2bf(float f) {
  unsigned u = __builtin_bit_cast(unsigned, f);
  u += 0x7FFFu + ((u >> 16) & 1u);           // RNE
  return (unsigned short)(u >> 16);
}
__device__ __forceinline__ float bf2f(unsigned short b) {
  unsigned u = ((unsigned)b) << 16;
  return __builtin_bit_cast(float, u);
}
// async global->LDS, 16B per lane. LDS dest is wave-uniform base + lane*16.
__device__ __forceinline__ void gload16(const unsigned short* g, unsigned short* l) {
  __builtin_amdgcn_global_load_lds((GV*)g, (LV*)l, 16, 0, 0);
}
__device__ __forceinline__ f32x4 mfma16(bf16x8 a, bf16x8 b, f32x4 c) {
  return __builtin_amdgcn_mfma_f32_16x16x32_bf16(a, b, c, 0, 0, 0);
}
__device__ __forceinline__ bf16x8 lds8(const unsigned short* p) {
  return __builtin_bit_cast(bf16x8, *(const ushort8v*)p);
}

// ---- dtype detect: freqs_cis[0] word is 0x3F800000 (fp32 cos(0)=1) or 0x00003F80 (bf16 pair) ----
__global__ void detect_dtype(const unsigned int* __restrict__ fc, int* __restrict__ flag) {
  if (threadIdx.x == 0 && blockIdx.x == 0)
    *flag = (fc[0] == 0x3F800000u) ? 0 : 1;   // 1 => inputs are bf16
}

// ---- x -> bf16 bits (copy if already bf16). 4 elems/thread ----
__global__ void cast_x(const void* __restrict__ src, unsigned short* __restrict__ dst,
                       const int* __restrict__ flag) {
  long t = (long)blockIdx.x * 256 + threadIdx.x;   // element group of 4
  if (*flag) {
    ((uint2*)dst)[t] = ((const uint2*)src)[t];
  } else {
    float4 f = ((const float4*)src)[t];
    ushort4 o;
    o.x = f2bf(f.x); o.y = f2bf(f.y); o.z = f2bf(f.z); o.w = f2bf(f.w);
    ((ushort4*)dst)[t] = o;
  }
}

// ---- transpose + cast: src (R x C) -> dst (C x R) bf16 ----
__global__ void transpose_cast(const void* __restrict__ src, unsigned short* __restrict__ dst,
                               int R, int C, const int* __restrict__ flag) {
  __shared__ unsigned short tile[32][33];   // +1 pad
  const int isbf = *flag;
  const int c0 = blockIdx.x * 32, r0 = blockIdx.y * 32;
  const int tx = threadIdx.x, ty = threadIdx.y;   // 32 x 8
  if (isbf) {
    const unsigned short* s = (const unsigned short*)src;
#pragma unroll
    for (int i = 0; i < 4; ++i)
      tile[ty + i * 8][tx] = s[(long)(r0 + ty + i * 8) * C + c0 + tx];
  } else {
    const float* s = (const float*)src;
#pragma unroll
    for (int i = 0; i < 4; ++i)
      tile[ty + i * 8][tx] = f2bf(s[(long)(r0 + ty + i * 8) * C + c0 + tx]);
  }
  __syncthreads();
#pragma unroll
  for (int i = 0; i < 4; ++i)
    dst[(long)(c0 + ty + i * 8) * R + r0 + tx] = tile[tx][ty + i * 8];
}

// ---- GEMM: C(MxN) = A(MxK,row) * Bt(NxK,row)^T ; bf16 in, fp32 acc ----
__global__ __launch_bounds__(256) void gemm_bt(const unsigned short* __restrict__ A,
                                               const unsigned short* __restrict__ Bt,
                                               void* __restrict__ Cv,
                                               int M, int N, int K, int outMode,
                                               const int* __restrict__ flag) {
  __shared__ unsigned short As[128 * 32];
  __shared__ unsigned short Bs[128 * 32];
  const int tid = threadIdx.x;
  const int lane = tid & 63, wave = tid >> 6;
  const int wm = (wave >> 1) * 64, wn = (wave & 1) * 64;
  const int lm = lane & 15, quad = lane >> 4;
  const long tileM = (long)blockIdx.y * 128, tileN = (long)blockIdx.x * 128;
  f32x4 acc[4][4] = {};
  const int r0 = tid >> 2, c0 = (tid & 3) * 8;
  const unsigned short* Ap = A + (tileM + r0) * (long)K + c0;
  const unsigned short* Bp = Bt + (tileN + r0) * (long)K + c0;
  for (int kt = 0; kt < K; kt += 32) {
    __syncthreads();
    gload16(Ap + kt, &As[tid * 8]);
    gload16(Ap + 64 * (long)K + kt, &As[2048 + tid * 8]);
    gload16(Bp + kt, &Bs[tid * 8]);
    gload16(Bp + 64 * (long)K + kt, &Bs[2048 + tid * 8]);
    __syncthreads();
    bf16x8 af[4], bfr[4];
#pragma unroll
    for (int i = 0; i < 4; ++i)
      af[i] = lds8(&As[(wm + i * 16 + lm) * 32 + quad * 8]);
#pragma unroll
    for (int j = 0; j < 4; ++j)
      bfr[j] = lds8(&Bs[(wn + j * 16 + lm) * 32 + quad * 8]);
#pragma unroll
    for (int i = 0; i < 4; ++i)
#pragma unroll
      for (int j = 0; j < 4; ++j)
        acc[i][j] = mfma16(af[i], bfr[j], acc[i][j]);
  }
  const int obf = (outMode == 2) ? *flag : outMode;
  if (obf) {
    unsigned short* C = (unsigned short*)Cv;
#pragma unroll
    for (int i = 0; i < 4; ++i)
#pragma unroll
      for (int j = 0; j < 4; ++j)
#pragma unroll
        for (int r = 0; r < 4; ++r)
          C[(tileM + wm + i * 16 + quad * 4 + r) * (long)N + tileN + wn + j * 16 + lm] =
              f2bf(acc[i][j][r]);
  } else {
    float* C = (float*)Cv;
#pragma unroll
    for (int i = 0; i < 4; ++i)
#pragma unroll
      for (int j = 0; j < 4; ++j)
#pragma unroll
        for (int r = 0; r < 4; ++r)
          C[(tileM + wm + i * 16 + quad * 4 + r) * (long)N + tileN + wn + j * 16 + lm] =
              acc[i][j][r];
  }
}

// ---- split qkv rows, apply RoPE to q/k, reorder. q,k -> (B,H,T,HD); v -> (B,KVH,HD,T) (transposed) ----
__global__ void rope_split(const unsigned short* __restrict__ qkv, const void* __restrict__ fcv,
                           const int* __restrict__ flag,
                           unsigned short* __restrict__ q, unsigned short* __restrict__ k,
                           unsigned short* __restrict__ v) {
  const int p = blockIdx.x * 256 + threadIdx.x;
  const int bt = blockIdx.y;
  const int b = bt >> 11, t = bt & (TSEQ - 1);
  const int isbf = *flag;
  const unsigned short* row = qkv + (long)bt * 6144;
  if (p < 2560) {   // rope on q (p<2048) or k
    int h, i;
    const unsigned short* srcp;
    unsigned short* dstp;
    if (p < 2048) {
      h = p >> 6; i = p & 63;
      srcp = row + h * 128 + 2 * i;
      dstp = q + ((long)(b * NH + h) * TSEQ + t) * HD + 2 * i;
    } else {
      int pp = p - 2048;
      h = pp >> 6; i = pp & 63;
      srcp = row + 4096 + h * 128 + 2 * i;
      dstp = k + ((long)(b * NKV + h) * TSEQ + t) * HD + 2 * i;
    }
    float c, s;
    long fo = ((long)t * 64 + i) * 2;
    if (isbf) {
      const unsigned short* fu = (const unsigned short*)fcv;
      c = bf2f(fu[fo]); s = bf2f(fu[fo + 1]);
    } else {
      const float* ff = (const float*)fcv;
      c = ff[fo]; s = ff[fo + 1];
    }
    float x0 = bf2f(srcp[0]), x1 = bf2f(srcp[1]);
    dstp[0] = f2bf(x0 * c - x1 * s);
    dstp[1] = f2bf(x1 * c + x0 * s);
  } else {          // v, transposed store: vT[((b*NKV+h)*HD + d) * T + t]
    int pp = p - 2560;
    int h = pp >> 6, i = pp & 63;
    const unsigned short* srcp = row + 5120 + h * 128 + 2 * i;
    unsigned short* base = v + ((long)(b * NKV + h) * HD + 2 * i) * TSEQ + t;
    base[0] = srcp[0];
    base[TSEQ] = srcp[1];
  }
}

// ---- flash attention v2: 128 q/block (32/wave), 32-key tiles, double-buffered K/V,
//      swizzled LDS (2-way max), no-max softmax (shift-invariance; scores |s|<~25) ----
// q:(B,NH,T,HD) k:(B,NKV,T,HD) vT:(B,NKV,HD,T) bf16 -> y:(B*T, DIM) bf16
__global__ __launch_bounds__(256, 3) void flash_attn(const unsigned short* __restrict__ q,
                                                     const unsigned short* __restrict__ k,
                                                     const unsigned short* __restrict__ vT,
                                                     unsigned short* __restrict__ y) {
  __shared__ unsigned short Ks[2][32 * 128];   // (key, d), chunk-swizzled
  __shared__ unsigned short Vs[2][128 * 32];   // (d, key), chunk-swizzled
  __shared__ unsigned short Pl[4][32 * 40];    // per-wave P (32q x 32k), stride 40
  const int tid = threadIdx.x;
  const int lane = tid & 63, wave = tid >> 6;
  const int lm = lane & 15, quad = lane >> 4;
  const int bh = blockIdx.y, b = bh >> 5, h = bh & 31, kvh = h >> 2;
  const int qi = (int)gridDim.x - 1 - (int)blockIdx.x;   // heavy blocks launch first
  const int q0 = qi * 128;
  const unsigned short* Qb = q + ((long)(b * NH + h) * TSEQ + q0 + wave * 32) * HD;
  const unsigned short* Kb = k + (long)(b * NKV + kvh) * TSEQ * HD;
  const unsigned short* Vb = vT + (long)(b * NKV + kvh) * HD * TSEQ;
  // Q fragments: A-layout, rows wave*32 + mi*16 + lm
  bf16x8 qf[2][4];
#pragma unroll
  for (int mi = 0; mi < 2; ++mi)
#pragma unroll
    for (int ks = 0; ks < 4; ++ks)
      qf[mi][ks] = __builtin_bit_cast(bf16x8,
          *(const ushort8v*)(Qb + (mi * 16 + lm) * HD + ks * 32 + quad * 8));
  f32x4 o[2][8] = {};
  float li[2][4] = {};
  const float scale = 0.08838834764831845f;  // 1/sqrt(128)
  // staging swizzle indices (global source permuted; LDS dest = base + lane*16B)
  const int krow = tid >> 4, kcl = ((tid & 15) ^ (krow & 7)) * 8;
  const int vrow = tid >> 2, vcl = ((tid & 3) ^ ((vrow >> 1) & 3)) * 8;
  const int ktiles = qi * 4 + 4;
  // prologue: stage tile 0 into buf 0
  {
    const unsigned short* Kg = Kb + 0;
    gload16(Kg + krow * HD + kcl, &Ks[0][tid * 8]);
    gload16(Kg + (16 + krow) * HD + kcl, &Ks[0][2048 + tid * 8]);
    const unsigned short* Vg = Vb + 0;
    gload16(Vg + (long)vrow * TSEQ + vcl, &Vs[0][tid * 8]);
    gload16(Vg + (long)(64 + vrow) * TSEQ + vcl, &Vs[0][2048 + tid * 8]);
  }
  for (int kt = 0; kt < ktiles; ++kt) {
    __syncthreads();   // drains buf[kt&1] loads; fences previous tile's LDS reads
    if (kt + 1 < ktiles) {   // prefetch kt+1 into other buffer (overlaps compute below)
      const int bi = (kt + 1) & 1;
      const unsigned short* Kg = Kb + (long)(kt + 1) * 32 * HD;
      gload16(Kg + krow * HD + kcl, &Ks[bi][tid * 8]);
      gload16(Kg + (16 + krow) * HD + kcl, &Ks[bi][2048 + tid * 8]);
      const unsigned short* Vg = Vb + (kt + 1) * 32;
      gload16(Vg + (long)vrow * TSEQ + vcl, &Vs[bi][tid * 8]);
      gload16(Vg + (long)(64 + vrow) * TSEQ + vcl, &Vs[bi][2048 + tid * 8]);
    }
    const unsigned short* KsB = Ks[kt & 1];
    const unsigned short* VsB = Vs[kt & 1];
    // S = Q K^T : 32q x 32k per wave
    f32x4 s[2][2] = {};
#pragma unroll
    for (int ni = 0; ni < 2; ++ni)
#pragma unroll
      for (int ks = 0; ks < 4; ++ks) {
        bf16x8 kf = lds8(&KsB[(ni * 16 + lm) * 128 + ((ks * 4 + quad) ^ (lm & 7)) * 8]);
        s[0][ni] = mfma16(qf[0][ks], kf, s[0][ni]);
        s[1][ni] = mfma16(qf[1][ks], kf, s[1][ni]);
      }
    // mask + exp (no max subtraction) + l accumulation + P to LDS
    unsigned short* PlW = &Pl[wave][0];
#pragma unroll
    for (int mi = 0; mi < 2; ++mi)
#pragma unroll
      for (int r = 0; r < 4; ++r) {
        const int qg = q0 + wave * 32 + mi * 16 + quad * 4 + r;
#pragma unroll
        for (int ni = 0; ni < 2; ++ni) {
          const int kg = kt * 32 + ni * 16 + lm;
          float p = (kg <= qg) ? __expf(s[mi][ni][r] * scale) : 0.f;
          li[mi][r] += p;
          PlW[(mi * 16 + quad * 4 + r) * 40 + ni * 16 + lm] = f2bf(p);
        }
      }
    bf16x8 pf0 = lds8(&PlW[lm * 40 + quad * 8]);
    bf16x8 pf1 = lds8(&PlW[(16 + lm) * 40 + quad * 8]);
#pragma unroll
    for (int db = 0; db < 8; ++db) {
      bf16x8 vf = lds8(&VsB[(db * 16 + lm) * 32 + (quad ^ ((lm >> 1) & 3)) * 8]);
      o[0][db] = mfma16(pf0, vf, o[0][db]);
      o[1][db] = mfma16(pf1, vf, o[1][db]);
    }
  }
  // final row-sum reduction (once per block) and store
  float inv[2][4];
#pragma unroll
  for (int mi = 0; mi < 2; ++mi)
#pragma unroll
    for (int r = 0; r < 4; ++r) {
      float l = li[mi][r];
      l += __shfl_xor(l, 1, 16);
      l += __shfl_xor(l, 2, 16);
      l += __shfl_xor(l, 4, 16);
      l += __shfl_xor(l, 8, 16);
      inv[mi][r] = 1.0f / l;
    }
  unsigned short* yo = y + ((long)b * TSEQ + q0 + wave * 32) * DIM + h * 128 + lm;
#pragma unroll
  for (int mi = 0; mi < 2; ++mi)
#pragma unroll
    for (int r = 0; r < 4; ++r) {
      unsigned short* yr = yo + (long)(mi * 16 + quad * 4 + r) * DIM;
#pragma unroll
      for (int db = 0; db < 8; ++db)
        yr[db * 16] = f2bf(o[mi][db][r] * inv[mi][r]);
    }
}

extern "C" void kernel_launch(void* const* d_in, const int* in_sizes, int n_in,
                              void* d_out, int out_size, void* d_ws, size_t ws_size,
                              hipStream_t stream) {
  const void* x  = d_in[0];
  const void* fc = d_in[1];
  const void* wq = d_in[2];
  const void* wk = d_in[3];
  const void* wv = d_in[4];
  const void* wo = d_in[5];
  char* ws = (char*)d_ws;
  int* flag             = (int*)ws;                         // 256 B reserved
  unsigned short* xb    = (unsigned short*)(ws + 256);      // 16,777,216 elems (reused as y)
  unsigned short* wqkvT = xb + 16777216L;                   // 25,165,824 elems (reused as q/k/vT)
  unsigned short* woT   = wqkvT + 25165824L;                // 16,777,216 elems
  unsigned short* qkvb  = woT + 16777216L;                  // 25,165,824 elems
  unsigned short* qb = wqkvT;
  unsigned short* kb = qb + 16777216L;
  unsigned short* vb = kb + 4194304L;
  unsigned short* yb = xb;

  detect_dtype<<<dim3(1), dim3(64), 0, stream>>>((const unsigned int*)fc, flag);
  cast_x<<<dim3(16384), dim3(256), 0, stream>>>(x, xb, flag);
  transpose_cast<<<dim3(128, 128), dim3(32, 8), 0, stream>>>(wq, wqkvT, 4096, 4096, flag);
  transpose_cast<<<dim3(32, 128), dim3(32, 8), 0, stream>>>(wk, wqkvT + 4096L * 4096, 4096, 1024, flag);
  transpose_cast<<<dim3(32, 128), dim3(32, 8), 0, stream>>>(wv, wqkvT + 5120L * 4096, 4096, 1024, flag);
  transpose_cast<<<dim3(128, 128), dim3(32, 8), 0, stream>>>(wo, woT, 4096, 4096, flag);
  gemm_bt<<<dim3(48, 32), dim3(256), 0, stream>>>(xb, wqkvT, (void*)qkvb, 4096, 6144, 4096, 1, flag);
  rope_split<<<dim3(12, 4096), dim3(256), 0, stream>>>(qkvb, fc, flag, qb, kb, vb);
  flash_attn<<<dim3(16, 64), dim3(256), 0, stream>>>(qb, kb, vb, yb);
  gemm_bt<<<dim3(32, 32), dim3(256), 0, stream>>>(yb, woT, d_out, 4096, 4096, 4096, 2, flag);
}

// Round 3
// 958.928 us; speedup vs baseline: 1.4038x; 1.0205x over previous
//
#include <hip/hip_runtime.h>

#define DIM  4096
#define NH   32
#define NKV  8
#define HD   128
#define BSZ  2
#define TSEQ 2048

typedef __bf16 bf16x8 __attribute__((ext_vector_type(8)));
typedef unsigned short ushort8v __attribute__((ext_vector_type(8)));
typedef float f32x4 __attribute__((ext_vector_type(4)));

typedef void GV __attribute__((address_space(1)));
typedef void LV __attribute__((address_space(3)));

__device__ __forceinline__ unsigned short f2bf(float f) {
  unsigned u = __builtin_bit_cast(unsigned, f);
  u += 0x7FFFu + ((u >> 16) & 1u);           // RNE
  return (unsigned short)(u >> 16);
}
__device__ __forceinline__ float bf2f(unsigned short b) {
  unsigned u = ((unsigned)b) << 16;
  return __builtin_bit_cast(float, u);
}
// async global->LDS, 16B per lane. LDS dest is wave-uniform base + lane*16.
__device__ __forceinline__ void gload16(const unsigned short* g, unsigned short* l) {
  __builtin_amdgcn_global_load_lds((GV*)g, (LV*)l, 16, 0, 0);
}
__device__ __forceinline__ f32x4 mfma16(bf16x8 a, bf16x8 b, f32x4 c) {
  return __builtin_amdgcn_mfma_f32_16x16x32_bf16(a, b, c, 0, 0, 0);
}
__device__ __forceinline__ bf16x8 lds8(const unsigned short* p) {
  return __builtin_bit_cast(bf16x8, *(const ushort8v*)p);
}

// ---- dtype detect: freqs_cis[0] word is 0x3F800000 (fp32 cos(0)=1) or 0x00003F80 (bf16 pair) ----
__global__ void detect_dtype(const unsigned int* __restrict__ fc, int* __restrict__ flag) {
  if (threadIdx.x == 0 && blockIdx.x == 0)
    *flag = (fc[0] == 0x3F800000u) ? 0 : 1;   // 1 => inputs are bf16
}

// ---- x -> bf16 bits (copy if already bf16). 4 elems/thread ----
__global__ void cast_x(const void* __restrict__ src, unsigned short* __restrict__ dst,
                       const int* __restrict__ flag) {
  long t = (long)blockIdx.x * 256 + threadIdx.x;   // element group of 4
  if (*flag) {
    ((uint2*)dst)[t] = ((const uint2*)src)[t];
  } else {
    float4 f = ((const float4*)src)[t];
    ushort4 o;
    o.x = f2bf(f.x); o.y = f2bf(f.y); o.z = f2bf(f.z); o.w = f2bf(f.w);
    ((ushort4*)dst)[t] = o;
  }
}

// ---- transpose + cast, 64x64 tile: src (R x C) -> dst (C x R) bf16. 16B reads AND writes ----
__global__ __launch_bounds__(256) void transpose64(const void* __restrict__ src,
                                                   unsigned short* __restrict__ dst,
                                                   int R, int C, const int* __restrict__ flag) {
  __shared__ unsigned short tile[64][68];   // stride 136 B (mult of 8, odd*8 -> spread banks)
  const int isbf = *flag;
  const int tid = threadIdx.x;
  const int c0g = blockIdx.x * 64, r0g = blockIdx.y * 64;
  const int cc = (tid & 15) * 4;
  if (isbf) {
    const unsigned short* s = (const unsigned short*)src;
#pragma unroll
    for (int it = 0; it < 4; ++it) {
      const int r = it * 16 + (tid >> 4);
      ushort4 v = *(const ushort4*)(s + (long)(r0g + r) * C + c0g + cc);
      *(ushort4*)&tile[r][cc] = v;
    }
  } else {
    const float* s = (const float*)src;
#pragma unroll
    for (int it = 0; it < 4; ++it) {
      const int r = it * 16 + (tid >> 4);
      float4 f = *(const float4*)(s + (long)(r0g + r) * C + c0g + cc);
      ushort4 v;
      v.x = f2bf(f.x); v.y = f2bf(f.y); v.z = f2bf(f.z); v.w = f2bf(f.w);
      *(ushort4*)&tile[r][cc] = v;
    }
  }
  __syncthreads();
#pragma unroll
  for (int it = 0; it < 2; ++it) {
    const int c = (tid >> 3) + it * 32;
    const int r0 = (tid & 7) * 8;
    ushort8v o;
#pragma unroll
    for (int u = 0; u < 8; ++u) o[u] = tile[r0 + u][c];
    *(ushort8v*)(dst + (long)(c0g + c) * R + r0g + r0) = o;
  }
}

// ================= fused QKV GEMM + RoPE + layout scatter =================
// A = x (4096 x 4096 bf16), Bt = wqkvT (6144 x 4096 bf16).
// cols [0,4096): rope -> q (B,NH,T,HD); [4096,5120): rope -> k (B,NKV,T,HD);
// [5120,6144): -> vT (B,NKV,HD,T).
__global__ __launch_bounds__(256) void gemm_qkv(const unsigned short* __restrict__ A,
                                                const unsigned short* __restrict__ Bt,
                                                const void* __restrict__ fcv,
                                                const int* __restrict__ flag,
                                                unsigned short* __restrict__ qo,
                                                unsigned short* __restrict__ ko,
                                                unsigned short* __restrict__ vo) {
  __shared__ unsigned short As[128 * 32];
  __shared__ unsigned short Bs[128 * 32];
  const int K = 4096;
  const int tid = threadIdx.x;
  const int lane = tid & 63, wave = tid >> 6;
  const int wm = (wave >> 1) * 64, wn = (wave & 1) * 64;
  const int lm = lane & 15, quad = lane >> 4;
  // 16x16 supertile swizzle (ntM=32, ntN=48 -> nSuperN=3)
  const int flat = blockIdx.x;
  const int sid = flat >> 8, within = flat & 255;
  const int sm = sid / 3, sn = sid - sm * 3;
  const long tileM = (long)(sm * 16 + (within & 15)) * 128;
  const long tileN = (long)(sn * 16 + (within >> 4)) * 128;
  f32x4 acc[4][4] = {};
  const int r0 = tid >> 2;
  const int c0 = (((tid & 3) ^ ((r0 >> 1) & 3))) * 8;   // chunk swizzle (matched on read)
  const unsigned short* Ap = A + (tileM + r0) * (long)K + c0;
  const unsigned short* Bp = Bt + (tileN + r0) * (long)K + c0;
  const int rsw = (quad ^ ((lm >> 1) & 3)) * 8;
  for (int kt = 0; kt < K; kt += 32) {
    __syncthreads();
    gload16(Ap + kt, &As[tid * 8]);
    gload16(Ap + 64 * (long)K + kt, &As[2048 + tid * 8]);
    gload16(Bp + kt, &Bs[tid * 8]);
    gload16(Bp + 64 * (long)K + kt, &Bs[2048 + tid * 8]);
    __syncthreads();
    bf16x8 af[4], bfr[4];
#pragma unroll
    for (int i = 0; i < 4; ++i)
      af[i] = lds8(&As[(wm + i * 16 + lm) * 32 + rsw]);
#pragma unroll
    for (int j = 0; j < 4; ++j)
      bfr[j] = lds8(&Bs[(wn + j * 16 + lm) * 32 + rsw]);
#pragma unroll
    for (int i = 0; i < 4; ++i)
#pragma unroll
      for (int j = 0; j < 4; ++j)
        acc[i][j] = mfma16(af[i], bfr[j], acc[i][j]);
  }
  // ---- epilogue: rope + scatter ----
  const int isbf = *flag;
  const int nb = (int)tileN + wn;          // 64-aligned; region uniform per wave
  if (nb < 5120) {                          // q or k: rope
    const int isk = (nb >= 4096);
    unsigned short* dst = isk ? ko : qo;
    const int hpb = isk ? NKV : NH;
    const int coff = isk ? 4096 : 0;
#pragma unroll
    for (int i = 0; i < 4; ++i)
#pragma unroll
      for (int r = 0; r < 4; ++r) {
        const int m = (int)tileM + wm + i * 16 + quad * 4 + r;
        const int b = m >> 11, t = m & (TSEQ - 1);
#pragma unroll
        for (int j = 0; j < 4; ++j) {
          const int n = nb + j * 16 + lm;
          float val = acc[i][j][r];
          float par = __shfl_xor(val, 1);
          const int ip = (n & 127) >> 1;
          float cz, sz;
          const long fo = (long)t * 64 + ip;
          if (isbf) {
            const unsigned short* fu = (const unsigned short*)fcv;
            cz = bf2f(fu[fo * 2]); sz = bf2f(fu[fo * 2 + 1]);
          } else {
            float2 cs = ((const float2*)fcv)[fo];
            cz = cs.x; sz = cs.y;
          }
          float out = (n & 1) ? (val * cz + par * sz) : (val * cz - par * sz);
          const int h = (n - coff) >> 7, d = n & 127;
          dst[((long)(b * hpb + h) * TSEQ + t) * HD + d] = f2bf(out);
        }
      }
  } else {                                  // v: transposed store vT[(b,kvh,d),t]
#pragma unroll
    for (int i = 0; i < 4; ++i)
#pragma unroll
      for (int r = 0; r < 4; ++r) {
        const int m = (int)tileM + wm + i * 16 + quad * 4 + r;
        const int b = m >> 11, t = m & (TSEQ - 1);
#pragma unroll
        for (int j = 0; j < 4; ++j) {
          const int n = nb + j * 16 + lm;
          const int h = (n - 5120) >> 7, d = n & 127;
          vo[((long)(b * NKV + h) * HD + d) * TSEQ + t] = f2bf(acc[i][j][r]);
        }
      }
  }
}

// ---- generic GEMM: C(MxN) = A(MxK,row) * Bt(NxK,row)^T ; swizzled LDS + supertiles ----
__global__ __launch_bounds__(256) void gemm_bt(const unsigned short* __restrict__ A,
                                               const unsigned short* __restrict__ Bt,
                                               void* __restrict__ Cv,
                                               int M, int N, int K, int outMode,
                                               const int* __restrict__ flag) {
  __shared__ unsigned short As[128 * 32];
  __shared__ unsigned short Bs[128 * 32];
  const int tid = threadIdx.x;
  const int lane = tid & 63, wave = tid >> 6;
  const int wm = (wave >> 1) * 64, wn = (wave & 1) * 64;
  const int lm = lane & 15, quad = lane >> 4;
  const int nSuperN = (N >> 7) >> 4;        // supertile cols (16x16 tiles)
  const int flat = blockIdx.x;
  const int sid = flat >> 8, within = flat & 255;
  const int sm = sid / nSuperN, sn = sid - sm * nSuperN;
  const long tileM = (long)(sm * 16 + (within & 15)) * 128;
  const long tileN = (long)(sn * 16 + (within >> 4)) * 128;
  f32x4 acc[4][4] = {};
  const int r0 = tid >> 2;
  const int c0 = (((tid & 3) ^ ((r0 >> 1) & 3))) * 8;
  const unsigned short* Ap = A + (tileM + r0) * (long)K + c0;
  const unsigned short* Bp = Bt + (tileN + r0) * (long)K + c0;
  const int rsw = (quad ^ ((lm >> 1) & 3)) * 8;
  for (int kt = 0; kt < K; kt += 32) {
    __syncthreads();
    gload16(Ap + kt, &As[tid * 8]);
    gload16(Ap + 64 * (long)K + kt, &As[2048 + tid * 8]);
    gload16(Bp + kt, &Bs[tid * 8]);
    gload16(Bp + 64 * (long)K + kt, &Bs[2048 + tid * 8]);
    __syncthreads();
    bf16x8 af[4], bfr[4];
#pragma unroll
    for (int i = 0; i < 4; ++i)
      af[i] = lds8(&As[(wm + i * 16 + lm) * 32 + rsw]);
#pragma unroll
    for (int j = 0; j < 4; ++j)
      bfr[j] = lds8(&Bs[(wn + j * 16 + lm) * 32 + rsw]);
#pragma unroll
    for (int i = 0; i < 4; ++i)
#pragma unroll
      for (int j = 0; j < 4; ++j)
        acc[i][j] = mfma16(af[i], bfr[j], acc[i][j]);
  }
  const int obf = (outMode == 2) ? *flag : outMode;
  if (obf) {
    unsigned short* C = (unsigned short*)Cv;
#pragma unroll
    for (int i = 0; i < 4; ++i)
#pragma unroll
      for (int j = 0; j < 4; ++j)
#pragma unroll
        for (int r = 0; r < 4; ++r)
          C[(tileM + wm + i * 16 + quad * 4 + r) * (long)N + tileN + wn + j * 16 + lm] =
              f2bf(acc[i][j][r]);
  } else {
    float* C = (float*)Cv;
#pragma unroll
    for (int i = 0; i < 4; ++i)
#pragma unroll
      for (int j = 0; j < 4; ++j)
#pragma unroll
        for (int r = 0; r < 4; ++r)
          C[(tileM + wm + i * 16 + quad * 4 + r) * (long)N + tileN + wn + j * 16 + lm] =
              acc[i][j][r];
  }
}

// ---- flash attention: 128 q/block (32/wave), 32-key tiles, double-buffered K/V,
//      swizzled LDS (2-way max), no-max softmax (shift-invariance; scores |s|<~25) ----
// q:(B,NH,T,HD) k:(B,NKV,T,HD) vT:(B,NKV,HD,T) bf16 -> y:(B*T, DIM) bf16
__global__ __launch_bounds__(256, 3) void flash_attn(const unsigned short* __restrict__ q,
                                                     const unsigned short* __restrict__ k,
                                                     const unsigned short* __restrict__ vT,
                                                     unsigned short* __restrict__ y) {
  __shared__ unsigned short Ks[2][32 * 128];   // (key, d), chunk-swizzled
  __shared__ unsigned short Vs[2][128 * 32];   // (d, key), chunk-swizzled
  __shared__ unsigned short Pl[4][32 * 40];    // per-wave P (32q x 32k), stride 40
  const int tid = threadIdx.x;
  const int lane = tid & 63, wave = tid >> 6;
  const int lm = lane & 15, quad = lane >> 4;
  const int bh = blockIdx.y, b = bh >> 5, h = bh & 31, kvh = h >> 2;
  const int qi = (int)gridDim.x - 1 - (int)blockIdx.x;   // heavy blocks launch first
  const int q0 = qi * 128;
  const unsigned short* Qb = q + ((long)(b * NH + h) * TSEQ + q0 + wave * 32) * HD;
  const unsigned short* Kb = k + (long)(b * NKV + kvh) * TSEQ * HD;
  const unsigned short* Vb = vT + (long)(b * NKV + kvh) * HD * TSEQ;
  bf16x8 qf[2][4];
#pragma unroll
  for (int mi = 0; mi < 2; ++mi)
#pragma unroll
    for (int ks = 0; ks < 4; ++ks)
      qf[mi][ks] = __builtin_bit_cast(bf16x8,
          *(const ushort8v*)(Qb + (mi * 16 + lm) * HD + ks * 32 + quad * 8));
  f32x4 o[2][8] = {};
  float li[2][4] = {};
  const float scale = 0.08838834764831845f;  // 1/sqrt(128)
  const int krow = tid >> 4, kcl = ((tid & 15) ^ (krow & 7)) * 8;
  const int vrow = tid >> 2, vcl = ((tid & 3) ^ ((vrow >> 1) & 3)) * 8;
  const int ktiles = qi * 4 + 4;
  {
    gload16(Kb + krow * HD + kcl, &Ks[0][tid * 8]);
    gload16(Kb + (16 + krow) * HD + kcl, &Ks[0][2048 + tid * 8]);
    gload16(Vb + (long)vrow * TSEQ + vcl, &Vs[0][tid * 8]);
    gload16(Vb + (long)(64 + vrow) * TSEQ + vcl, &Vs[0][2048 + tid * 8]);
  }
  for (int kt = 0; kt < ktiles; ++kt) {
    __syncthreads();
    if (kt + 1 < ktiles) {
      const int bi = (kt + 1) & 1;
      const unsigned short* Kg = Kb + (long)(kt + 1) * 32 * HD;
      gload16(Kg + krow * HD + kcl, &Ks[bi][tid * 8]);
      gload16(Kg + (16 + krow) * HD + kcl, &Ks[bi][2048 + tid * 8]);
      const unsigned short* Vg = Vb + (kt + 1) * 32;
      gload16(Vg + (long)vrow * TSEQ + vcl, &Vs[bi][tid * 8]);
      gload16(Vg + (long)(64 + vrow) * TSEQ + vcl, &Vs[bi][2048 + tid * 8]);
    }
    const unsigned short* KsB = Ks[kt & 1];
    const unsigned short* VsB = Vs[kt & 1];
    f32x4 s[2][2] = {};
#pragma unroll
    for (int ni = 0; ni < 2; ++ni)
#pragma unroll
      for (int ks = 0; ks < 4; ++ks) {
        bf16x8 kf = lds8(&KsB[(ni * 16 + lm) * 128 + ((ks * 4 + quad) ^ (lm & 7)) * 8]);
        s[0][ni] = mfma16(qf[0][ks], kf, s[0][ni]);
        s[1][ni] = mfma16(qf[1][ks], kf, s[1][ni]);
      }
    unsigned short* PlW = &Pl[wave][0];
#pragma unroll
    for (int mi = 0; mi < 2; ++mi)
#pragma unroll
      for (int r = 0; r < 4; ++r) {
        const int qg = q0 + wave * 32 + mi * 16 + quad * 4 + r;
#pragma unroll
        for (int ni = 0; ni < 2; ++ni) {
          const int kg = kt * 32 + ni * 16 + lm;
          float p = (kg <= qg) ? __expf(s[mi][ni][r] * scale) : 0.f;
          li[mi][r] += p;
          PlW[(mi * 16 + quad * 4 + r) * 40 + ni * 16 + lm] = f2bf(p);
        }
      }
    bf16x8 pf0 = lds8(&PlW[lm * 40 + quad * 8]);
    bf16x8 pf1 = lds8(&PlW[(16 + lm) * 40 + quad * 8]);
#pragma unroll
    for (int db = 0; db < 8; ++db) {
      bf16x8 vf = lds8(&VsB[(db * 16 + lm) * 32 + (quad ^ ((lm >> 1) & 3)) * 8]);
      o[0][db] = mfma16(pf0, vf, o[0][db]);
      o[1][db] = mfma16(pf1, vf, o[1][db]);
    }
  }
  float inv[2][4];
#pragma unroll
  for (int mi = 0; mi < 2; ++mi)
#pragma unroll
    for (int r = 0; r < 4; ++r) {
      float l = li[mi][r];
      l += __shfl_xor(l, 1, 16);
      l += __shfl_xor(l, 2, 16);
      l += __shfl_xor(l, 4, 16);
      l += __shfl_xor(l, 8, 16);
      inv[mi][r] = 1.0f / l;
    }
  unsigned short* yo = y + ((long)b * TSEQ + q0 + wave * 32) * DIM + h * 128 + lm;
#pragma unroll
  for (int mi = 0; mi < 2; ++mi)
#pragma unroll
    for (int r = 0; r < 4; ++r) {
      unsigned short* yr = yo + (long)(mi * 16 + quad * 4 + r) * DIM;
#pragma unroll
      for (int db = 0; db < 8; ++db)
        yr[db * 16] = f2bf(o[mi][db][r] * inv[mi][r]);
    }
}

extern "C" void kernel_launch(void* const* d_in, const int* in_sizes, int n_in,
                              void* d_out, int out_size, void* d_ws, size_t ws_size,
                              hipStream_t stream) {
  const void* x  = d_in[0];
  const void* fc = d_in[1];
  const void* wq = d_in[2];
  const void* wk = d_in[3];
  const void* wv = d_in[4];
  const void* wo = d_in[5];
  char* ws = (char*)d_ws;
  int* flag             = (int*)ws;                         // 256 B reserved
  unsigned short* xb    = (unsigned short*)(ws + 256);      // 16,777,216 elems (reused as y)
  unsigned short* wqkvT = xb + 16777216L;                   // 25,165,824 elems
  unsigned short* woT   = wqkvT + 25165824L;                // 16,777,216 elems
  unsigned short* qb    = woT + 16777216L;                  // 16,777,216 elems
  unsigned short* kb    = qb + 16777216L;                   //  4,194,304 elems
  unsigned short* vb    = kb + 4194304L;                    //  4,194,304 elems
  unsigned short* yb    = xb;

  detect_dtype<<<dim3(1), dim3(64), 0, stream>>>((const unsigned int*)fc, flag);
  cast_x<<<dim3(16384), dim3(256), 0, stream>>>(x, xb, flag);
  transpose64<<<dim3(64, 64), dim3(256), 0, stream>>>(wq, wqkvT, 4096, 4096, flag);
  transpose64<<<dim3(16, 64), dim3(256), 0, stream>>>(wk, wqkvT + 4096L * 4096, 4096, 1024, flag);
  transpose64<<<dim3(16, 64), dim3(256), 0, stream>>>(wv, wqkvT + 5120L * 4096, 4096, 1024, flag);
  transpose64<<<dim3(64, 64), dim3(256), 0, stream>>>(wo, woT, 4096, 4096, flag);
  gemm_qkv<<<dim3(1536), dim3(256), 0, stream>>>(xb, wqkvT, fc, flag, qb, kb, vb);
  flash_attn<<<dim3(16, 64), dim3(256), 0, stream>>>(qb, kb, vb, yb);
  gemm_bt<<<dim3(1024), dim3(256), 0, stream>>>(yb, woT, d_out, 4096, 4096, 4096, 2, flag);
}